// Round 1
// baseline (1281.460 us; speedup 1.0000x reference)
//
#include <hip/hip_runtime.h>
#include <hip/hip_bf16.h>

#define N_NODES 100000
#define N_EDGES 1600000
#define D 128
#define N_LAYERS 4
#define LN_EPS 1e-5f

// ---------------- CSR build ----------------
__global__ void k_zero_counts(int* __restrict__ counts) {
    int i = blockIdx.x * blockDim.x + threadIdx.x;
    if (i < N_NODES) counts[i] = 0;
}

__global__ void k_count(const int* __restrict__ ei, int* __restrict__ counts) {
    int e = blockIdx.x * blockDim.x + threadIdx.x;
    if (e < N_EDGES) {
        int dst = ei[N_EDGES + e];
        atomicAdd(&counts[dst], 1);
    }
}

__global__ void k_dinv(const int* __restrict__ counts, float* __restrict__ dinv) {
    int i = blockIdx.x * blockDim.x + threadIdx.x;
    if (i < N_NODES) dinv[i] = rsqrtf((float)counts[i] + 1.0f);
}

// single-block exclusive scan of counts -> row_start (also duplicated into cursor)
__global__ void k_scan(const int* __restrict__ counts, int* __restrict__ row_start,
                       int* __restrict__ cursor) {
    __shared__ int partial[1024];
    const int CHUNK = (N_NODES + 1023) / 1024;  // 98
    int tid = threadIdx.x;
    int lo = tid * CHUNK;
    int hi = lo + CHUNK; if (hi > N_NODES) hi = N_NODES;
    int s = 0;
    for (int i = lo; i < hi; i++) s += counts[i];
    partial[tid] = s;
    __syncthreads();
    for (int off = 1; off < 1024; off <<= 1) {
        int v = (tid >= off) ? partial[tid - off] : 0;
        __syncthreads();
        partial[tid] += v;
        __syncthreads();
    }
    int running = partial[tid] - s;  // exclusive prefix
    for (int i = lo; i < hi; i++) {
        row_start[i] = running;
        cursor[i]   = running;
        running += counts[i];
    }
}

__global__ void k_fill(const int* __restrict__ ei, const float* __restrict__ dinv,
                       int* __restrict__ cursor, int* __restrict__ col,
                       float* __restrict__ wnorm) {
    int e = blockIdx.x * blockDim.x + threadIdx.x;
    if (e < N_EDGES) {
        int src = ei[e];
        int dst = ei[N_EDGES + e];
        int p = atomicAdd(&cursor[dst], 1);
        col[p]   = src;
        wnorm[p] = dinv[src] * dinv[dst];
    }
}

// ---------------- per-layer GEMM: HW = H @ W  (f32, LDS tiled) ----------------
// block: 256 thr; tile BM=64 rows x BN=64 cols; thread tile 4x4
__global__ __launch_bounds__(256) void k_gemm(const float* __restrict__ H,
                                              const float* __restrict__ W,
                                              float* __restrict__ HW) {
    __shared__ float sW[128 * 64];   // [k][c-in-half]
    __shared__ float sHT[128 * 64];  // [k][r]
    int t = threadIdx.x;
    int rbase = blockIdx.x * 64;
    int cbase = blockIdx.y * 64;

    // load W column-half: 128x64 floats
    {
        const float4* Wg = (const float4*)W;   // row stride = 32 float4
        float4* sW4 = (float4*)sW;
        #pragma unroll
        for (int i = 0; i < 8; i++) {
            int f = t + 256 * i;     // 0..2047 float4s
            int k  = f >> 4;
            int c4 = f & 15;
            sW4[k * 16 + c4] = Wg[k * 32 + (cbase >> 2) + c4];
        }
    }
    // load H tile transposed: sHT[k][r]
    {
        int r  = t >> 2;
        int k0 = (t & 3) * 32;
        int grow = rbase + r;
        if (grow < N_NODES) {
            const float4* Hg = (const float4*)(H + (size_t)grow * D + k0);
            #pragma unroll
            for (int i = 0; i < 8; i++) {
                float4 v = Hg[i];
                int k = k0 + i * 4;
                sHT[(k + 0) * 64 + r] = v.x;
                sHT[(k + 1) * 64 + r] = v.y;
                sHT[(k + 2) * 64 + r] = v.z;
                sHT[(k + 3) * 64 + r] = v.w;
            }
        } else {
            #pragma unroll
            for (int i = 0; i < 8; i++) {
                int k = k0 + i * 4;
                sHT[(k + 0) * 64 + r] = 0.f;
                sHT[(k + 1) * 64 + r] = 0.f;
                sHT[(k + 2) * 64 + r] = 0.f;
                sHT[(k + 3) * 64 + r] = 0.f;
            }
        }
    }
    __syncthreads();

    int tx = t & 15, ty = t >> 4;
    const float4* sW4 = (const float4*)sW;
    const float4* sH4 = (const float4*)sHT;
    float acc[4][4] = {};
    #pragma unroll 8
    for (int k = 0; k < 128; k++) {
        float4 wv = sW4[k * 16 + tx];
        float4 hv = sH4[k * 16 + ty];
        acc[0][0] += hv.x * wv.x; acc[0][1] += hv.x * wv.y; acc[0][2] += hv.x * wv.z; acc[0][3] += hv.x * wv.w;
        acc[1][0] += hv.y * wv.x; acc[1][1] += hv.y * wv.y; acc[1][2] += hv.y * wv.z; acc[1][3] += hv.y * wv.w;
        acc[2][0] += hv.z * wv.x; acc[2][1] += hv.z * wv.y; acc[2][2] += hv.z * wv.z; acc[2][3] += hv.z * wv.w;
        acc[3][0] += hv.w * wv.x; acc[3][1] += hv.w * wv.y; acc[3][2] += hv.w * wv.z; acc[3][3] += hv.w * wv.w;
    }

    int r0 = rbase + ty * 4, c0 = cbase + tx * 4;
    #pragma unroll
    for (int i = 0; i < 4; i++) {
        int r = r0 + i;
        if (r < N_NODES) {
            float4 o = make_float4(acc[i][0], acc[i][1], acc[i][2], acc[i][3]);
            *(float4*)(HW + (size_t)r * D + c0) = o;
        }
    }
}

// ------------- fused aggregation + self-loop + bias + LN + ReLU -------------
// one wave (64 lanes) per node; lane handles dims {2*lane, 2*lane+1}
__global__ __launch_bounds__(256) void k_agg(const float* __restrict__ HW,
                                             const int* __restrict__ row_start,
                                             const int* __restrict__ counts,
                                             const int* __restrict__ col,
                                             const float* __restrict__ wnorm,
                                             const float* __restrict__ dinv,
                                             const float* __restrict__ b,
                                             const float* __restrict__ gamma,
                                             const float* __restrict__ beta,
                                             float* __restrict__ out) {
    int wave = threadIdx.x >> 6;
    int lane = threadIdx.x & 63;
    int n = blockIdx.x * 4 + wave;
    if (n >= N_NODES) return;

    int start = row_start[n];
    int cnt   = counts[n];
    const float2* HW2 = (const float2*)HW;

    float ax = 0.f, ay = 0.f;
    for (int j = 0; j < cnt; j++) {
        int   s = col[start + j];
        float w = wnorm[start + j];
        float2 v = HW2[(size_t)s * 64 + lane];
        ax += v.x * w; ay += v.y * w;
    }
    // self-loop
    {
        float di = dinv[n];
        float w  = di * di;
        float2 v = HW2[(size_t)n * 64 + lane];
        ax += v.x * w; ay += v.y * w;
    }
    ax += b[lane * 2]; ay += b[lane * 2 + 1];

    // LayerNorm over 128 dims
    float s = ax + ay;
    #pragma unroll
    for (int off = 32; off >= 1; off >>= 1) s += __shfl_xor(s, off);
    float mean = s * (1.0f / 128.0f);
    float cx = ax - mean, cy = ay - mean;
    float q = cx * cx + cy * cy;
    #pragma unroll
    for (int off = 32; off >= 1; off >>= 1) q += __shfl_xor(q, off);
    float rstd = rsqrtf(q * (1.0f / 128.0f) + LN_EPS);

    float ox = cx * rstd * gamma[lane * 2]     + beta[lane * 2];
    float oy = cy * rstd * gamma[lane * 2 + 1] + beta[lane * 2 + 1];
    ox = fmaxf(ox, 0.f); oy = fmaxf(oy, 0.f);
    ((float2*)out)[(size_t)n * 64 + lane] = make_float2(ox, oy);
}

extern "C" void kernel_launch(void* const* d_in, const int* in_sizes, int n_in,
                              void* d_out, int out_size, void* d_ws, size_t ws_size,
                              hipStream_t stream) {
    const float* x      = (const float*)d_in[0];
    const int*   ei     = (const int*)d_in[1];
    const float* Ws     = (const float*)d_in[2];
    const float* bs     = (const float*)d_in[3];
    const float* gammas = (const float*)d_in[4];
    const float* betas  = (const float*)d_in[5];
    float* out = (float*)d_out;

    char* ws = (char*)d_ws;
    int*   counts    = (int*)ws;   ws += (size_t)N_NODES * 4;
    int*   row_start = (int*)ws;   ws += (size_t)N_NODES * 4;
    int*   cursor    = (int*)ws;   ws += (size_t)N_NODES * 4;
    float* dinv      = (float*)ws; ws += (size_t)N_NODES * 4;
    int*   col       = (int*)ws;   ws += (size_t)N_EDGES * 4;
    float* wnorm     = (float*)ws; ws += (size_t)N_EDGES * 4;
    float* hw        = (float*)ws; ws += (size_t)N_NODES * D * 4;

    k_zero_counts<<<(N_NODES + 255) / 256, 256, 0, stream>>>(counts);
    k_count<<<(N_EDGES + 255) / 256, 256, 0, stream>>>(ei, counts);
    k_dinv<<<(N_NODES + 255) / 256, 256, 0, stream>>>(counts, dinv);
    k_scan<<<1, 1024, 0, stream>>>(counts, row_start, cursor);
    k_fill<<<(N_EDGES + 255) / 256, 256, 0, stream>>>(ei, dinv, cursor, col, wnorm);

    for (int l = 0; l < N_LAYERS; l++) {
        const float* hin = (l == 0) ? x : out;
        dim3 g((N_NODES + 63) / 64, 2);
        k_gemm<<<g, 256, 0, stream>>>(hin, Ws + (size_t)l * D * D, hw);
        k_agg<<<(N_NODES + 3) / 4, 256, 0, stream>>>(hw, row_start, counts, col, wnorm,
                                                     dinv, bs + l * D, gammas + l * D,
                                                     betas + l * D, out);
    }
}

// Round 2
// 811.476 us; speedup vs baseline: 1.5792x; 1.5792x over previous
//
#include <hip/hip_runtime.h>
#include <hip/hip_bf16.h>

#define N_NODES 100000
#define N_EDGES 1600000
#define D 128
#define N_LAYERS 4
#define LN_EPS 1e-5f
#define NB_SCAN ((N_NODES + 255) / 256)   // 391

// ---------------- helpers ----------------
__device__ __forceinline__ unsigned short f2bf(float f) {
    __hip_bfloat16 h = __float2bfloat16(f);
    return *reinterpret_cast<unsigned short*>(&h);
}
__device__ __forceinline__ float bf_lo(unsigned u) {
    union { unsigned u; float f; } x; x.u = u << 16; return x.f;
}
__device__ __forceinline__ float bf_hi(unsigned u) {
    union { unsigned u; float f; } x; x.u = u & 0xffff0000u; return x.f;
}

// ---------------- CSR build ----------------
__global__ void k_zero_counts(int* __restrict__ counts) {
    int i = blockIdx.x * blockDim.x + threadIdx.x;
    if (i < N_NODES) counts[i] = 0;
}

__global__ void k_count(const int* __restrict__ ei, int* __restrict__ counts) {
    int e = blockIdx.x * blockDim.x + threadIdx.x;
    if (e < N_EDGES) {
        int dst = ei[N_EDGES + e];
        atomicAdd(&counts[dst], 1);
    }
}

__global__ void k_dinv(const int* __restrict__ counts, float* __restrict__ dinv) {
    int i = blockIdx.x * blockDim.x + threadIdx.x;
    if (i < N_NODES) dinv[i] = rsqrtf((float)counts[i] + 1.0f);
}

// hierarchical scan: (1) per-block exclusive + block sums
__global__ __launch_bounds__(256) void k_scan1(const int* __restrict__ counts,
                                               int* __restrict__ row_start,
                                               int* __restrict__ blocksums) {
    __shared__ int buf[256];
    int tid = threadIdx.x;
    int i = blockIdx.x * 256 + tid;
    int c = (i < N_NODES) ? counts[i] : 0;
    buf[tid] = c;
    __syncthreads();
    #pragma unroll
    for (int off = 1; off < 256; off <<= 1) {
        int v = (tid >= off) ? buf[tid - off] : 0;
        __syncthreads();
        buf[tid] += v;
        __syncthreads();
    }
    if (i < N_NODES) row_start[i] = buf[tid] - c;  // block-local exclusive
    if (tid == 255) blocksums[blockIdx.x] = buf[255];
}

// (2) single-block scan of 391 block sums -> exclusive block offsets
__global__ __launch_bounds__(512) void k_scan2(const int* __restrict__ blocksums,
                                               int* __restrict__ blockoff) {
    __shared__ int buf[512];
    int tid = threadIdx.x;
    int c = (tid < NB_SCAN) ? blocksums[tid] : 0;
    buf[tid] = c;
    __syncthreads();
    #pragma unroll
    for (int off = 1; off < 512; off <<= 1) {
        int v = (tid >= off) ? buf[tid - off] : 0;
        __syncthreads();
        buf[tid] += v;
        __syncthreads();
    }
    if (tid < NB_SCAN) blockoff[tid] = buf[tid] - c;
}

// (3) add block offsets, duplicate into cursor
__global__ __launch_bounds__(256) void k_scan3(const int* __restrict__ blockoff,
                                               int* __restrict__ row_start,
                                               int* __restrict__ cursor) {
    int i = blockIdx.x * 256 + threadIdx.x;
    if (i < N_NODES) {
        int rs = row_start[i] + blockoff[blockIdx.x];
        row_start[i] = rs;
        cursor[i] = rs;
    }
}

__global__ void k_fill(const int* __restrict__ ei, const float* __restrict__ dinv,
                       int* __restrict__ cursor, int* __restrict__ col,
                       float* __restrict__ wnorm) {
    int e = blockIdx.x * blockDim.x + threadIdx.x;
    if (e < N_EDGES) {
        int src = ei[e];
        int dst = ei[N_EDGES + e];
        int p = atomicAdd(&cursor[dst], 1);
        col[p]   = src;
        wnorm[p] = dinv[src] * dinv[dst];
    }
}

// ---------------- per-layer GEMM: HWb = bf16(H @ W) ----------------
// block: 256 thr; tile BM=64 rows x BN=64 cols; thread tile 4x4
__global__ __launch_bounds__(256) void k_gemm(const float* __restrict__ H,
                                              const float* __restrict__ W,
                                              unsigned short* __restrict__ HWb) {
    __shared__ float sW[128 * 64];   // [k][c-in-half]
    __shared__ float sHT[128 * 64];  // [k][r]
    int t = threadIdx.x;
    int rbase = blockIdx.x * 64;
    int cbase = blockIdx.y * 64;

    {
        const float4* Wg = (const float4*)W;   // row stride = 32 float4
        float4* sW4 = (float4*)sW;
        #pragma unroll
        for (int i = 0; i < 8; i++) {
            int f = t + 256 * i;
            int k  = f >> 4;
            int c4 = f & 15;
            sW4[k * 16 + c4] = Wg[k * 32 + (cbase >> 2) + c4];
        }
    }
    {
        int r  = t >> 2;
        int k0 = (t & 3) * 32;
        int grow = rbase + r;
        if (grow < N_NODES) {
            const float4* Hg = (const float4*)(H + (size_t)grow * D + k0);
            #pragma unroll
            for (int i = 0; i < 8; i++) {
                float4 v = Hg[i];
                int k = k0 + i * 4;
                sHT[(k + 0) * 64 + r] = v.x;
                sHT[(k + 1) * 64 + r] = v.y;
                sHT[(k + 2) * 64 + r] = v.z;
                sHT[(k + 3) * 64 + r] = v.w;
            }
        } else {
            #pragma unroll
            for (int i = 0; i < 8; i++) {
                int k = k0 + i * 4;
                sHT[(k + 0) * 64 + r] = 0.f;
                sHT[(k + 1) * 64 + r] = 0.f;
                sHT[(k + 2) * 64 + r] = 0.f;
                sHT[(k + 3) * 64 + r] = 0.f;
            }
        }
    }
    __syncthreads();

    int tx = t & 15, ty = t >> 4;
    const float4* sW4 = (const float4*)sW;
    const float4* sH4 = (const float4*)sHT;
    float acc[4][4] = {};
    #pragma unroll 8
    for (int k = 0; k < 128; k++) {
        float4 wv = sW4[k * 16 + tx];
        float4 hv = sH4[k * 16 + ty];
        acc[0][0] += hv.x * wv.x; acc[0][1] += hv.x * wv.y; acc[0][2] += hv.x * wv.z; acc[0][3] += hv.x * wv.w;
        acc[1][0] += hv.y * wv.x; acc[1][1] += hv.y * wv.y; acc[1][2] += hv.y * wv.z; acc[1][3] += hv.y * wv.w;
        acc[2][0] += hv.z * wv.x; acc[2][1] += hv.z * wv.y; acc[2][2] += hv.z * wv.z; acc[2][3] += hv.z * wv.w;
        acc[3][0] += hv.w * wv.x; acc[3][1] += hv.w * wv.y; acc[3][2] += hv.w * wv.z; acc[3][3] += hv.w * wv.w;
    }

    int r0 = rbase + ty * 4, c0 = cbase + tx * 4;
    #pragma unroll
    for (int i = 0; i < 4; i++) {
        int r = r0 + i;
        if (r < N_NODES) {
            ushort4 o;
            o.x = f2bf(acc[i][0]); o.y = f2bf(acc[i][1]);
            o.z = f2bf(acc[i][2]); o.w = f2bf(acc[i][3]);
            *(ushort4*)(HWb + (size_t)r * D + c0) = o;
        }
    }
}

// ------------- fused aggregation + self-loop + bias + LN + ReLU -------------
// one HALF-WAVE (32 lanes) per node; lane handles dims [4*sl .. 4*sl+3]
__global__ __launch_bounds__(256) void k_agg(const unsigned short* __restrict__ HWb,
                                             const int* __restrict__ row_start,
                                             const int* __restrict__ counts,
                                             const int* __restrict__ col,
                                             const float* __restrict__ wnorm,
                                             const float* __restrict__ dinv,
                                             const float* __restrict__ b,
                                             const float* __restrict__ gamma,
                                             const float* __restrict__ beta,
                                             float* __restrict__ out) {
    int half = threadIdx.x >> 5;            // 0..7 within block
    int sl   = threadIdx.x & 31;            // lane within half-wave
    int n = blockIdx.x * 8 + half;
    if (n >= N_NODES) return;

    int start = row_start[n];
    int cnt   = counts[n];
    const uint2* HW4 = (const uint2*)HWb;   // row = 32 × uint2 (4 bf16 each)

    float a0 = 0.f, a1 = 0.f, a2 = 0.f, a3 = 0.f;
    for (int j = 0; j < cnt; j++) {
        int   s = col[start + j];
        float w = wnorm[start + j];
        uint2 v = HW4[(size_t)s * 32 + sl];
        a0 += w * bf_lo(v.x); a1 += w * bf_hi(v.x);
        a2 += w * bf_lo(v.y); a3 += w * bf_hi(v.y);
    }
    // self-loop
    {
        float di = dinv[n];
        float w  = di * di;
        uint2 v = HW4[(size_t)n * 32 + sl];
        a0 += w * bf_lo(v.x); a1 += w * bf_hi(v.x);
        a2 += w * bf_lo(v.y); a3 += w * bf_hi(v.y);
    }
    float4 bv = *(const float4*)(b + 4 * sl);
    a0 += bv.x; a1 += bv.y; a2 += bv.z; a3 += bv.w;

    // LayerNorm over 128 dims (reduce across 32 lanes)
    float s = a0 + a1 + a2 + a3;
    #pragma unroll
    for (int off = 16; off >= 1; off >>= 1) s += __shfl_xor(s, off);
    float mean = s * (1.0f / 128.0f);
    float c0 = a0 - mean, c1 = a1 - mean, c2 = a2 - mean, c3 = a3 - mean;
    float q = c0 * c0 + c1 * c1 + c2 * c2 + c3 * c3;
    #pragma unroll
    for (int off = 16; off >= 1; off >>= 1) q += __shfl_xor(q, off);
    float rstd = rsqrtf(q * (1.0f / 128.0f) + LN_EPS);

    float4 gv = *(const float4*)(gamma + 4 * sl);
    float4 tv = *(const float4*)(beta  + 4 * sl);
    float4 o;
    o.x = fmaxf(c0 * rstd * gv.x + tv.x, 0.f);
    o.y = fmaxf(c1 * rstd * gv.y + tv.y, 0.f);
    o.z = fmaxf(c2 * rstd * gv.z + tv.z, 0.f);
    o.w = fmaxf(c3 * rstd * gv.w + tv.w, 0.f);
    ((float4*)(out + (size_t)n * D))[sl] = o;
}

extern "C" void kernel_launch(void* const* d_in, const int* in_sizes, int n_in,
                              void* d_out, int out_size, void* d_ws, size_t ws_size,
                              hipStream_t stream) {
    const float* x      = (const float*)d_in[0];
    const int*   ei     = (const int*)d_in[1];
    const float* Ws     = (const float*)d_in[2];
    const float* bs     = (const float*)d_in[3];
    const float* gammas = (const float*)d_in[4];
    const float* betas  = (const float*)d_in[5];
    float* out = (float*)d_out;

    char* ws = (char*)d_ws;
    int*   counts    = (int*)ws;   ws += (size_t)N_NODES * 4;
    int*   row_start = (int*)ws;   ws += (size_t)N_NODES * 4;
    int*   cursor    = (int*)ws;   ws += (size_t)N_NODES * 4;
    float* dinv      = (float*)ws; ws += (size_t)N_NODES * 4;
    int*   blocksums = (int*)ws;   ws += 512 * 4;
    int*   blockoff  = (int*)ws;   ws += 512 * 4;
    int*   col       = (int*)ws;   ws += (size_t)N_EDGES * 4;
    float* wnorm     = (float*)ws; ws += (size_t)N_EDGES * 4;
    unsigned short* hwb = (unsigned short*)ws; ws += (size_t)N_NODES * D * 2;

    k_zero_counts<<<(N_NODES + 255) / 256, 256, 0, stream>>>(counts);
    k_count<<<(N_EDGES + 255) / 256, 256, 0, stream>>>(ei, counts);
    k_dinv<<<(N_NODES + 255) / 256, 256, 0, stream>>>(counts, dinv);
    k_scan1<<<NB_SCAN, 256, 0, stream>>>(counts, row_start, blocksums);
    k_scan2<<<1, 512, 0, stream>>>(blocksums, blockoff);
    k_scan3<<<NB_SCAN, 256, 0, stream>>>(blockoff, row_start, cursor);
    k_fill<<<(N_EDGES + 255) / 256, 256, 0, stream>>>(ei, dinv, cursor, col, wnorm);

    for (int l = 0; l < N_LAYERS; l++) {
        const float* hin = (l == 0) ? x : out;
        dim3 g((N_NODES + 63) / 64, 2);
        k_gemm<<<g, 256, 0, stream>>>(hin, Ws + (size_t)l * D * D, hwb);
        k_agg<<<(N_NODES + 7) / 8, 256, 0, stream>>>(hwb, row_start, counts, col, wnorm,
                                                     dinv, bs + l * D, gammas + l * D,
                                                     betas + l * D, out);
    }
}

// Round 3
// 560.477 us; speedup vs baseline: 2.2864x; 1.4478x over previous
//
#include <hip/hip_runtime.h>
#include <hip/hip_bf16.h>

#define N_NODES 100000
#define N_EDGES 1600000
#define D 128
#define N_LAYERS 4
#define LN_EPS 1e-5f
#define NB_SCAN ((N_NODES + 255) / 256)   // 391

typedef _Float16 half8 __attribute__((ext_vector_type(8)));
typedef _Float16 half4v __attribute__((ext_vector_type(4)));
typedef float f32x4 __attribute__((ext_vector_type(4)));

// ---------------- CSR build ----------------
__global__ void k_count(const int* __restrict__ ei, int* __restrict__ counts) {
    int e = blockIdx.x * blockDim.x + threadIdx.x;
    if (e < N_EDGES) {
        int dst = ei[N_EDGES + e];
        atomicAdd(&counts[dst], 1);
    }
}

__global__ void k_dinv(const int* __restrict__ counts, float* __restrict__ dinv) {
    int i = blockIdx.x * blockDim.x + threadIdx.x;
    if (i < N_NODES) dinv[i] = rsqrtf((float)counts[i] + 1.0f);
}

__global__ __launch_bounds__(256) void k_scan1(const int* __restrict__ counts,
                                               int* __restrict__ row_start,
                                               int* __restrict__ blocksums) {
    __shared__ int buf[256];
    int tid = threadIdx.x;
    int i = blockIdx.x * 256 + tid;
    int c = (i < N_NODES) ? counts[i] : 0;
    buf[tid] = c;
    __syncthreads();
    #pragma unroll
    for (int off = 1; off < 256; off <<= 1) {
        int v = (tid >= off) ? buf[tid - off] : 0;
        __syncthreads();
        buf[tid] += v;
        __syncthreads();
    }
    if (i < N_NODES) row_start[i] = buf[tid] - c;
    if (tid == 255) blocksums[blockIdx.x] = buf[255];
}

__global__ __launch_bounds__(512) void k_scan2(const int* __restrict__ blocksums,
                                               int* __restrict__ blockoff) {
    __shared__ int buf[512];
    int tid = threadIdx.x;
    int c = (tid < NB_SCAN) ? blocksums[tid] : 0;
    buf[tid] = c;
    __syncthreads();
    #pragma unroll
    for (int off = 1; off < 512; off <<= 1) {
        int v = (tid >= off) ? buf[tid - off] : 0;
        __syncthreads();
        buf[tid] += v;
        __syncthreads();
    }
    if (tid < NB_SCAN) blockoff[tid] = buf[tid] - c;
}

__global__ __launch_bounds__(256) void k_scan3(const int* __restrict__ blockoff,
                                               int* __restrict__ row_start,
                                               int* __restrict__ cursor) {
    int i = blockIdx.x * 256 + threadIdx.x;
    if (i < N_NODES) {
        int rs = row_start[i] + blockoff[blockIdx.x];
        row_start[i] = rs;
        cursor[i] = rs;
    }
}

// packed scatter: one uint2 (col, wnorm) per edge -> one cache line touched
__global__ void k_fill(const int* __restrict__ ei, const float* __restrict__ dinv,
                       int* __restrict__ cursor, uint2* __restrict__ colw) {
    int e = blockIdx.x * blockDim.x + threadIdx.x;
    if (e < N_EDGES) {
        int src = ei[e];
        int dst = ei[N_EDGES + e];
        int p = atomicAdd(&cursor[dst], 1);
        uint2 v;
        v.x = (unsigned)src;
        v.y = __float_as_uint(dinv[src] * dinv[dst]);
        colw[p] = v;
    }
}

// ---------------- precision prep ----------------
// x (f32) -> h (f16)
__global__ __launch_bounds__(256) void k_cvt_x(const float* __restrict__ X,
                                               _Float16* __restrict__ H) {
    int i = blockIdx.x * 256 + threadIdx.x;  // one float4 per thread
    if (i < N_NODES * D / 4) {
        float4 v = ((const float4*)X)[i];
        half4v o;
        o[0] = (_Float16)v.x; o[1] = (_Float16)v.y;
        o[2] = (_Float16)v.z; o[3] = (_Float16)v.w;
        ((half4v*)H)[i] = o;
    }
}

// Ws (4x128x128 f32, [l][k][n]) -> WT (4x128x128 f16, [l][n][k])
__global__ __launch_bounds__(256) void k_prep_w(const float* __restrict__ Ws,
                                                _Float16* __restrict__ WT) {
    int idx = blockIdx.x * 256 + threadIdx.x;     // 65536 total
    int l = idx >> 14;
    int k = (idx >> 7) & 127;
    int n = idx & 127;
    WT[(size_t)l * D * D + (size_t)n * D + k] = (_Float16)Ws[(size_t)l * D * D + (size_t)k * D + n];
}

// ---------------- MFMA GEMM: HW = H @ W  (f16 in/out, f32 accum) ----------------
// block = 4 waves (2 M x 2 N); wave tile 32x64; block tile 64 rows x 128 cols
__global__ __launch_bounds__(256) void k_gemm(const _Float16* __restrict__ H,
                                              const _Float16* __restrict__ WT,
                                              _Float16* __restrict__ HW) {
    int t = threadIdx.x;
    int wave = t >> 6;
    int lane = t & 63;
    int wm = wave & 1, wn = wave >> 1;
    int m0 = blockIdx.x * 64 + wm * 32;
    int n0 = wn * 64;
    int lr = lane & 15;
    int kg = lane >> 4;

    f32x4 acc[2][4] = {};

    const half8* Hr[2];
    #pragma unroll
    for (int mi = 0; mi < 2; mi++) {
        int row = m0 + mi * 16 + lr;
        row = row < N_NODES ? row : N_NODES - 1;
        Hr[mi] = (const half8*)(H + (size_t)row * D);
    }
    const half8* Wr[4];
    #pragma unroll
    for (int ni = 0; ni < 4; ni++)
        Wr[ni] = (const half8*)(WT + (size_t)(n0 + ni * 16 + lr) * D);

    #pragma unroll
    for (int ks = 0; ks < 4; ks++) {
        half8 a0 = Hr[0][ks * 4 + kg];
        half8 a1 = Hr[1][ks * 4 + kg];
        half8 b0 = Wr[0][ks * 4 + kg];
        half8 b1 = Wr[1][ks * 4 + kg];
        half8 b2 = Wr[2][ks * 4 + kg];
        half8 b3 = Wr[3][ks * 4 + kg];
        acc[0][0] = __builtin_amdgcn_mfma_f32_16x16x32_f16(a0, b0, acc[0][0], 0, 0, 0);
        acc[0][1] = __builtin_amdgcn_mfma_f32_16x16x32_f16(a0, b1, acc[0][1], 0, 0, 0);
        acc[0][2] = __builtin_amdgcn_mfma_f32_16x16x32_f16(a0, b2, acc[0][2], 0, 0, 0);
        acc[0][3] = __builtin_amdgcn_mfma_f32_16x16x32_f16(a0, b3, acc[0][3], 0, 0, 0);
        acc[1][0] = __builtin_amdgcn_mfma_f32_16x16x32_f16(a1, b0, acc[1][0], 0, 0, 0);
        acc[1][1] = __builtin_amdgcn_mfma_f32_16x16x32_f16(a1, b1, acc[1][1], 0, 0, 0);
        acc[1][2] = __builtin_amdgcn_mfma_f32_16x16x32_f16(a1, b2, acc[1][2], 0, 0, 0);
        acc[1][3] = __builtin_amdgcn_mfma_f32_16x16x32_f16(a1, b3, acc[1][3], 0, 0, 0);
    }

    #pragma unroll
    for (int mi = 0; mi < 2; mi++) {
        #pragma unroll
        for (int r = 0; r < 4; r++) {
            int row = m0 + mi * 16 + kg * 4 + r;
            if (row < N_NODES) {
                _Float16* dst = HW + (size_t)row * D;
                #pragma unroll
                for (int ni = 0; ni < 4; ni++)
                    dst[n0 + ni * 16 + lr] = (_Float16)acc[mi][ni][r];
            }
        }
    }
}

// ------------- fused aggregation + self-loop + bias + LN + ReLU -------------
// one half-wave (32 lanes) per node; lane handles dims [4*sl .. 4*sl+3]
__global__ __launch_bounds__(256) void k_agg(const _Float16* __restrict__ HWh,
                                             const int* __restrict__ row_start,
                                             const int* __restrict__ counts,
                                             const uint2* __restrict__ colw,
                                             const float* __restrict__ dinv,
                                             const float* __restrict__ b,
                                             const float* __restrict__ gamma,
                                             const float* __restrict__ beta,
                                             _Float16* __restrict__ hout,
                                             float* __restrict__ fout,
                                             int last) {
    int half = threadIdx.x >> 5;
    int sl   = threadIdx.x & 31;
    int n = blockIdx.x * 8 + half;
    if (n >= N_NODES) return;

    int start = row_start[n];
    int cnt   = counts[n];
    const half4v* tbl = (const half4v*)HWh;   // row = 32 x half4
    const uint2* cw = colw + start;

    float a0 = 0.f, a1 = 0.f, a2 = 0.f, a3 = 0.f;
    int j = 0;
    for (; j + 2 <= cnt; j += 2) {
        uint2 e0 = cw[j];
        uint2 e1 = cw[j + 1];
        half4v v0 = tbl[(size_t)e0.x * 32 + sl];
        half4v v1 = tbl[(size_t)e1.x * 32 + sl];
        float w0 = __uint_as_float(e0.y);
        float w1 = __uint_as_float(e1.y);
        a0 += w0 * (float)v0[0] + w1 * (float)v1[0];
        a1 += w0 * (float)v0[1] + w1 * (float)v1[1];
        a2 += w0 * (float)v0[2] + w1 * (float)v1[2];
        a3 += w0 * (float)v0[3] + w1 * (float)v1[3];
    }
    if (j < cnt) {
        uint2 e0 = cw[j];
        half4v v0 = tbl[(size_t)e0.x * 32 + sl];
        float w0 = __uint_as_float(e0.y);
        a0 += w0 * (float)v0[0];
        a1 += w0 * (float)v0[1];
        a2 += w0 * (float)v0[2];
        a3 += w0 * (float)v0[3];
    }
    {   // self-loop
        float di = dinv[n];
        float w  = di * di;
        half4v v = tbl[(size_t)n * 32 + sl];
        a0 += w * (float)v[0];
        a1 += w * (float)v[1];
        a2 += w * (float)v[2];
        a3 += w * (float)v[3];
    }
    float4 bv = *(const float4*)(b + 4 * sl);
    a0 += bv.x; a1 += bv.y; a2 += bv.z; a3 += bv.w;

    float s = a0 + a1 + a2 + a3;
    #pragma unroll
    for (int off = 16; off >= 1; off >>= 1) s += __shfl_xor(s, off);
    float mean = s * (1.0f / 128.0f);
    float c0 = a0 - mean, c1 = a1 - mean, c2 = a2 - mean, c3 = a3 - mean;
    float q = c0 * c0 + c1 * c1 + c2 * c2 + c3 * c3;
    #pragma unroll
    for (int off = 16; off >= 1; off >>= 1) q += __shfl_xor(q, off);
    float rstd = rsqrtf(q * (1.0f / 128.0f) + LN_EPS);

    float4 gv = *(const float4*)(gamma + 4 * sl);
    float4 tv = *(const float4*)(beta  + 4 * sl);
    float o0 = fmaxf(c0 * rstd * gv.x + tv.x, 0.f);
    float o1 = fmaxf(c1 * rstd * gv.y + tv.y, 0.f);
    float o2 = fmaxf(c2 * rstd * gv.z + tv.z, 0.f);
    float o3 = fmaxf(c3 * rstd * gv.w + tv.w, 0.f);

    if (last) {
        ((float4*)(fout + (size_t)n * D))[sl] = make_float4(o0, o1, o2, o3);
    } else {
        half4v o;
        o[0] = (_Float16)o0; o[1] = (_Float16)o1;
        o[2] = (_Float16)o2; o[3] = (_Float16)o3;
        ((half4v*)(hout + (size_t)n * D))[sl] = o;
    }
}

extern "C" void kernel_launch(void* const* d_in, const int* in_sizes, int n_in,
                              void* d_out, int out_size, void* d_ws, size_t ws_size,
                              hipStream_t stream) {
    const float* x      = (const float*)d_in[0];
    const int*   ei     = (const int*)d_in[1];
    const float* Ws     = (const float*)d_in[2];
    const float* bs     = (const float*)d_in[3];
    const float* gammas = (const float*)d_in[4];
    const float* betas  = (const float*)d_in[5];
    float* out = (float*)d_out;

    char* ws = (char*)d_ws;
    int*   counts    = (int*)ws;   ws += (size_t)N_NODES * 4;
    int*   row_start = (int*)ws;   ws += (size_t)N_NODES * 4;
    int*   cursor    = (int*)ws;   ws += (size_t)N_NODES * 4;
    float* dinv      = (float*)ws; ws += (size_t)N_NODES * 4;
    int*   blocksums = (int*)ws;   ws += 512 * 4;
    int*   blockoff  = (int*)ws;   ws += 512 * 4;
    uint2* colw      = (uint2*)ws; ws += (size_t)N_EDGES * 8;
    _Float16* h      = (_Float16*)ws; ws += (size_t)N_NODES * D * 2;
    _Float16* hw     = (_Float16*)ws; ws += (size_t)N_NODES * D * 2;
    _Float16* wt     = (_Float16*)ws; ws += (size_t)N_LAYERS * D * D * 2;

    hipMemsetAsync(counts, 0, (size_t)N_NODES * 4, stream);
    k_count<<<(N_EDGES + 255) / 256, 256, 0, stream>>>(ei, counts);
    k_dinv<<<(N_NODES + 255) / 256, 256, 0, stream>>>(counts, dinv);
    k_scan1<<<NB_SCAN, 256, 0, stream>>>(counts, row_start, blocksums);
    k_scan2<<<1, 512, 0, stream>>>(blocksums, blockoff);
    k_scan3<<<NB_SCAN, 256, 0, stream>>>(blockoff, row_start, cursor);
    k_fill<<<(N_EDGES + 255) / 256, 256, 0, stream>>>(ei, dinv, cursor, colw);
    k_cvt_x<<<(N_NODES * D / 4 + 255) / 256, 256, 0, stream>>>(x, h);
    k_prep_w<<<(N_LAYERS * D * D) / 256, 256, 0, stream>>>(Ws, wt);

    for (int l = 0; l < N_LAYERS; l++) {
        k_gemm<<<(N_NODES + 63) / 64, 256, 0, stream>>>(h, wt + (size_t)l * D * D, hw);
        int last = (l == N_LAYERS - 1) ? 1 : 0;
        k_agg<<<(N_NODES + 7) / 8, 256, 0, stream>>>(hw, row_start, counts, colw,
                                                     dinv, bs + l * D, gammas + l * D,
                                                     betas + l * D, h, out, last);
    }
}